// Round 5
// baseline (125.246 us; speedup 1.0000x reference)
//
#include <hip/hip_runtime.h>
#include <hip/hip_bf16.h>
#include <math.h>

// Problem constants
#define BB 32
#define TT 4096
#define CC 64
#define DD 512
#define NW 31          // number of windows
#define WIN 256
#define HOP 128
#define NROWS (BB * NW)   // 992

typedef float f32x4 __attribute__((ext_vector_type(4)));

// ---------------------------------------------------------------------------
// Kernel 1: band power via folded Goertzel.
// Fold: e^{-2pi i f (t+128)/256} = (-1)^f e^{-2pi i f t/256}, so
//   even f: X_f = sum_{t<128} u_t w^{ft},  u_t = x_t + x_{t+128}
//   odd  f: X_f = sum_{t<128} v_t w^{ft},  v_t = x_t - x_{t+128}
// -> every chain runs 128 steps instead of 256.
// One block per (b,n) window; 512 threads = 8 waves; c = tid&63, g = tid>>6.
// Wave g owns freqs f = 1+g+8j, j=0..6 (f>50 discarded; parity(f) uniform
// per wave -> u/v select is wave-uniform).
// Goertzel: s_t = y_t + coef*s1 - s2, coef = 2cos(2pi f/256);
// |X|^2 = s1^2 + s2^2 - coef*s1*s2 (N-independent identity).
// LDS: u[128][64] | v[128][64] = 64 KB, re-aliased as bpart[8][5][64] after
// the compute barrier.
// ---------------------------------------------------------------------------
__global__ __launch_bounds__(512) void k_bandpower(const float* __restrict__ x,
                                                   float* __restrict__ feat) {
    __shared__ float lds[16384];         // 64 KB
    float* u = lds;                      // [128][64]
    float* v = lds + 8192;               // [128][64]

    const int tid = threadIdx.x;
    const int c   = tid & 63;
    const int g   = tid >> 6;            // wave id 0..7
    const int blk = blockIdx.x;          // 0..991
    const int b   = blk / NW;
    const int n   = blk % NW;

    // staged fold: read both halves once, write u,v (coalesced f32x4)
    const size_t winBase = ((size_t)b * TT + (size_t)n * HOP) * CC;
    const f32x4* h0 = (const f32x4*)(x + winBase);              // t = 0..127
    const f32x4* h1 = (const f32x4*)(x + winBase + 128 * CC);   // t = 128..255
    f32x4* u4 = (f32x4*)u;
    f32x4* v4 = (f32x4*)v;
    for (int i = tid; i < 2048; i += 512) {
        const f32x4 a  = h0[i];
        const f32x4 bb = h1[i];
        u4[i] = a + bb;
        v4[i] = a - bb;
    }
    __syncthreads();

    // 7 Goertzel chains per thread, 128 steps, on u (even f) or v (odd f)
    float coef[7], s1[7], s2[7];
#pragma unroll
    for (int j = 0; j < 7; ++j) {
        const int f = 1 + g + 8 * j;
        coef[j] = 2.0f * cospif((float)f * (1.0f / 128.0f)); // 2cos(2pi f/256)
        s1[j] = 0.0f;
        s2[j] = 0.0f;
    }
    // parity(f) = parity(1+g): g odd -> f even -> u; g even -> f odd -> v
    const float* src = ((g & 1) ? u : v) + c;

#pragma unroll 4
    for (int tt = 0; tt < 128; ++tt) {
        const float xv = src[tt * 64];
#pragma unroll
        for (int j = 0; j < 7; ++j) {
            const float sn = fmaf(coef[j], s1[j], xv - s2[j]);
            s2[j] = s1[j];
            s1[j] = sn;
        }
    }
    __syncthreads();   // done reading u/v; lds is re-aliased below

    // per-thread band sums
    float pb[5] = {0.0f, 0.0f, 0.0f, 0.0f, 0.0f};
#pragma unroll
    for (int j = 0; j < 7; ++j) {
        const int f = 1 + g + 8 * j;
        if (f > 50) continue;            // wave-uniform guard
        const float p = fmaf(s1[j], s1[j],
                        fmaf(s2[j], s2[j], -coef[j] * s1[j] * s2[j]));
        if (f <= 4)             pb[0] += p;
        if (f >= 4 && f <= 8)   pb[1] += p;
        if (f >= 8 && f <= 13)  pb[2] += p;
        if (f >= 13 && f <= 30) pb[3] += p;
        if (f >= 30)            pb[4] += p;
    }

    // cross-wave reduction via re-aliased LDS (each (g,k,c) written once)
    float (*bpart)[5][64] = (float (*)[5][64])lds;
#pragma unroll
    for (int k = 0; k < 5; ++k) bpart[g][k][c] = pb[k];
    __syncthreads();

    const float wband[5] = {1.0f / 4.0f, 1.0f / 5.0f, 1.0f / 6.0f,
                            1.0f / 18.0f, 1.0f / 21.0f};
    for (int idx = tid; idx < 320; idx += 512) {
        const int k  = idx >> 6;
        const int cc = idx & 63;
        float s = 0.0f;
#pragma unroll
        for (int gg = 0; gg < 8; ++gg) s += bpart[gg][k][cc];
        feat[(size_t)blk * 320 + idx] = s * wband[k];
    }
}

// ---------------------------------------------------------------------------
// Kernel 2: MLP. 8 rows per block, 256 threads.
// h = relu(feat @ W1 + b1); feat2 = h @ W2 + b2.
// W1: (320,256) row-major, W2: (256,512) row-major.
// ---------------------------------------------------------------------------
__global__ __launch_bounds__(256) void k_mlp(const float* __restrict__ feat,
                                             const float* __restrict__ W1,
                                             const float* __restrict__ b1,
                                             const float* __restrict__ W2,
                                             const float* __restrict__ b2,
                                             float* __restrict__ feat2) {
    __shared__ float fs[8][320];
    __shared__ float hs[8][256];

    const int tid  = threadIdx.x;
    const int row0 = blockIdx.x * 8;

    for (int i = tid; i < 8 * 320; i += 256)
        ((float*)fs)[i] = feat[(size_t)row0 * 320 + i];
    __syncthreads();

    // phase 1: hidden (256 wide), thread owns column tid
    float acc[8];
    {
        const float bias = b1[tid];
#pragma unroll
        for (int r = 0; r < 8; ++r) acc[r] = bias;
        for (int i = 0; i < 320; ++i) {
            const float w = W1[(size_t)i * 256 + tid];
#pragma unroll
            for (int r = 0; r < 8; ++r) acc[r] = fmaf(fs[r][i], w, acc[r]);
        }
#pragma unroll
        for (int r = 0; r < 8; ++r) hs[r][tid] = fmaxf(acc[r], 0.0f);
    }
    __syncthreads();

    // phase 2: output (512 wide), thread owns columns tid and tid+256
    float o0[8], o1[8];
    {
        const float bias0 = b2[tid];
        const float bias1 = b2[tid + 256];
#pragma unroll
        for (int r = 0; r < 8; ++r) { o0[r] = bias0; o1[r] = bias1; }
        for (int i = 0; i < 256; ++i) {
            const float w0 = W2[(size_t)i * 512 + tid];
            const float w1 = W2[(size_t)i * 512 + tid + 256];
#pragma unroll
            for (int r = 0; r < 8; ++r) {
                const float h = hs[r][i];
                o0[r] = fmaf(h, w0, o0[r]);
                o1[r] = fmaf(h, w1, o1[r]);
            }
        }
    }
#pragma unroll
    for (int r = 0; r < 8; ++r) {
        feat2[(size_t)(row0 + r) * 512 + tid]       = o0[r];
        feat2[(size_t)(row0 + r) * 512 + tid + 256] = o1[r];
    }
}

// ---------------------------------------------------------------------------
// Kernel 3: linear interpolation nW=31 -> T=4096 (align_corners=False).
// Grid-stride restructure: 2048 blocks (8/CU), block owns a fixed t-pair
// (t = 2*blockIdx + (tid>>7)) and loops over all b. pos/i0/i1/w are
// loop-invariant -> inner loop is 2 coalesced loads + 1 NT store.
// Amortizes workgroup dispatch 32x vs the old 65536-block version.
// ---------------------------------------------------------------------------
__global__ __launch_bounds__(256) void k_interp(const float* __restrict__ feat2,
                                                float* __restrict__ out) {
    const int tid = threadIdx.x;
    const int t   = blockIdx.x * 2 + (tid >> 7);   // fixed t for this thread
    const int d4  = tid & 127;                     // float4 index within row

    float pos = ((float)t + 0.5f) * (31.0f / 4096.0f) - 0.5f;
    pos = fminf(fmaxf(pos, 0.0f), 30.0f);
    const int   i0 = (int)pos;            // pos >= 0, trunc == floor
    const int   i1 = min(i0 + 1, 30);
    const float w  = pos - (float)i0;
    const float w0 = 1.0f - w;

#pragma unroll 2
    for (int b = 0; b < BB; ++b) {
        const f32x4* r0 = (const f32x4*)(feat2 + ((size_t)b * NW + i0) * DD);
        const f32x4* r1 = (const f32x4*)(feat2 + ((size_t)b * NW + i1) * DD);
        f32x4* o = (f32x4*)(out + ((size_t)b * TT + t) * DD);
        const f32x4 res = r0[d4] * w0 + r1[d4] * w;
        __builtin_nontemporal_store(res, &o[d4]);
    }
}

// ---------------------------------------------------------------------------
extern "C" void kernel_launch(void* const* d_in, const int* in_sizes, int n_in,
                              void* d_out, int out_size, void* d_ws, size_t ws_size,
                              hipStream_t stream) {
    const float* x  = (const float*)d_in[0];
    const float* W1 = (const float*)d_in[1];
    const float* b1 = (const float*)d_in[2];
    const float* W2 = (const float*)d_in[3];
    const float* b2 = (const float*)d_in[4];
    float* out = (float*)d_out;

    float* feat  = (float*)d_ws;                 // NROWS*320 floats = 1.27 MB
    float* feat2 = feat + (size_t)NROWS * 320;   // NROWS*512 floats = 2.03 MB

    k_bandpower<<<NROWS, 512, 0, stream>>>(x, feat);
    k_mlp<<<NROWS / 8, 256, 0, stream>>>(feat, W1, b1, W2, b2, feat2);
    k_interp<<<TT / 2, 256, 0, stream>>>(feat2, out);
}

// Round 6
// 113.221 us; speedup vs baseline: 1.1062x; 1.1062x over previous
//
#include <hip/hip_runtime.h>
#include <hip/hip_bf16.h>
#include <math.h>

// Problem constants
#define BB 32
#define TT 4096
#define CC 64
#define DD 512
#define NW 31          // number of windows
#define WIN 256
#define HOP 128
#define NROWS (BB * NW)   // 992

typedef float f32x4 __attribute__((ext_vector_type(4)));

// ---------------------------------------------------------------------------
// Kernel 1: band power via folded Goertzel.
// Fold: e^{-2pi i f (t+128)/256} = (-1)^f e^{-2pi i f t/256}, so
//   even f: X_f = sum_{t<128} u_t w^{ft},  u_t = x_t + x_{t+128}
//   odd  f: X_f = sum_{t<128} v_t w^{ft},  v_t = x_t - x_{t+128}
// -> every chain runs 128 steps instead of 256.
// One block per (b,n) window; 512 threads = 8 waves; c = tid&63, g = tid>>6.
// Wave g owns freqs f = 1+g+8j, j=0..6 (f>50 discarded; parity(f) uniform
// per wave -> u/v select is wave-uniform).
// Goertzel: s_t = y_t + coef*s1 - s2, coef = 2cos(2pi f/256);
// |X|^2 = s1^2 + s2^2 - coef*s1*s2 (N-independent identity).
// LDS: u[128][64] | v[128][64] = 64 KB, re-aliased as bpart[8][5][64] after
// the compute barrier.
// ---------------------------------------------------------------------------
__global__ __launch_bounds__(512) void k_bandpower(const float* __restrict__ x,
                                                   float* __restrict__ feat) {
    __shared__ float lds[16384];         // 64 KB
    float* u = lds;                      // [128][64]
    float* v = lds + 8192;               // [128][64]

    const int tid = threadIdx.x;
    const int c   = tid & 63;
    const int g   = tid >> 6;            // wave id 0..7
    const int blk = blockIdx.x;          // 0..991
    const int b   = blk / NW;
    const int n   = blk % NW;

    // staged fold: read both halves once, write u,v (coalesced f32x4)
    const size_t winBase = ((size_t)b * TT + (size_t)n * HOP) * CC;
    const f32x4* h0 = (const f32x4*)(x + winBase);              // t = 0..127
    const f32x4* h1 = (const f32x4*)(x + winBase + 128 * CC);   // t = 128..255
    f32x4* u4 = (f32x4*)u;
    f32x4* v4 = (f32x4*)v;
    for (int i = tid; i < 2048; i += 512) {
        const f32x4 a  = h0[i];
        const f32x4 bb = h1[i];
        u4[i] = a + bb;
        v4[i] = a - bb;
    }
    __syncthreads();

    // 7 Goertzel chains per thread, 128 steps, on u (even f) or v (odd f)
    float coef[7], s1[7], s2[7];
#pragma unroll
    for (int j = 0; j < 7; ++j) {
        const int f = 1 + g + 8 * j;
        coef[j] = 2.0f * cospif((float)f * (1.0f / 128.0f)); // 2cos(2pi f/256)
        s1[j] = 0.0f;
        s2[j] = 0.0f;
    }
    // parity(f) = parity(1+g): g odd -> f even -> u; g even -> f odd -> v
    const float* src = ((g & 1) ? u : v) + c;

#pragma unroll 4
    for (int tt = 0; tt < 128; ++tt) {
        const float xv = src[tt * 64];
#pragma unroll
        for (int j = 0; j < 7; ++j) {
            const float sn = fmaf(coef[j], s1[j], xv - s2[j]);
            s2[j] = s1[j];
            s1[j] = sn;
        }
    }
    __syncthreads();   // done reading u/v; lds is re-aliased below

    // per-thread band sums
    float pb[5] = {0.0f, 0.0f, 0.0f, 0.0f, 0.0f};
#pragma unroll
    for (int j = 0; j < 7; ++j) {
        const int f = 1 + g + 8 * j;
        if (f > 50) continue;            // wave-uniform guard
        const float p = fmaf(s1[j], s1[j],
                        fmaf(s2[j], s2[j], -coef[j] * s1[j] * s2[j]));
        if (f <= 4)             pb[0] += p;
        if (f >= 4 && f <= 8)   pb[1] += p;
        if (f >= 8 && f <= 13)  pb[2] += p;
        if (f >= 13 && f <= 30) pb[3] += p;
        if (f >= 30)            pb[4] += p;
    }

    // cross-wave reduction via re-aliased LDS (each (g,k,c) written once)
    float (*bpart)[5][64] = (float (*)[5][64])lds;
#pragma unroll
    for (int k = 0; k < 5; ++k) bpart[g][k][c] = pb[k];
    __syncthreads();

    const float wband[5] = {1.0f / 4.0f, 1.0f / 5.0f, 1.0f / 6.0f,
                            1.0f / 18.0f, 1.0f / 21.0f};
    for (int idx = tid; idx < 320; idx += 512) {
        const int k  = idx >> 6;
        const int cc = idx & 63;
        float s = 0.0f;
#pragma unroll
        for (int gg = 0; gg < 8; ++gg) s += bpart[gg][k][cc];
        feat[(size_t)blk * 320 + idx] = s * wband[k];
    }
}

// ---------------------------------------------------------------------------
// Kernel 2: MLP. 8 rows per block, 256 threads.
// h = relu(feat @ W1 + b1); feat2 = h @ W2 + b2.
// W1: (320,256) row-major, W2: (256,512) row-major.
// ---------------------------------------------------------------------------
__global__ __launch_bounds__(256) void k_mlp(const float* __restrict__ feat,
                                             const float* __restrict__ W1,
                                             const float* __restrict__ b1,
                                             const float* __restrict__ W2,
                                             const float* __restrict__ b2,
                                             float* __restrict__ feat2) {
    __shared__ float fs[8][320];
    __shared__ float hs[8][256];

    const int tid  = threadIdx.x;
    const int row0 = blockIdx.x * 8;

    for (int i = tid; i < 8 * 320; i += 256)
        ((float*)fs)[i] = feat[(size_t)row0 * 320 + i];
    __syncthreads();

    // phase 1: hidden (256 wide), thread owns column tid
    float acc[8];
    {
        const float bias = b1[tid];
#pragma unroll
        for (int r = 0; r < 8; ++r) acc[r] = bias;
        for (int i = 0; i < 320; ++i) {
            const float w = W1[(size_t)i * 256 + tid];
#pragma unroll
            for (int r = 0; r < 8; ++r) acc[r] = fmaf(fs[r][i], w, acc[r]);
        }
#pragma unroll
        for (int r = 0; r < 8; ++r) hs[r][tid] = fmaxf(acc[r], 0.0f);
    }
    __syncthreads();

    // phase 2: output (512 wide), thread owns columns tid and tid+256
    float o0[8], o1[8];
    {
        const float bias0 = b2[tid];
        const float bias1 = b2[tid + 256];
#pragma unroll
        for (int r = 0; r < 8; ++r) { o0[r] = bias0; o1[r] = bias1; }
        for (int i = 0; i < 256; ++i) {
            const float w0 = W2[(size_t)i * 512 + tid];
            const float w1 = W2[(size_t)i * 512 + tid + 256];
#pragma unroll
            for (int r = 0; r < 8; ++r) {
                const float h = hs[r][i];
                o0[r] = fmaf(h, w0, o0[r]);
                o1[r] = fmaf(h, w1, o1[r]);
            }
        }
    }
#pragma unroll
    for (int r = 0; r < 8; ++r) {
        feat2[(size_t)(row0 + r) * 512 + tid]       = o0[r];
        feat2[(size_t)(row0 + r) * 512 + tid + 256] = o1[r];
    }
}

// ---------------------------------------------------------------------------
// Kernel 3: linear interpolation nW=31 -> T=4096 (align_corners=False).
// 16384 blocks; block owns 8 CONSECUTIVE t of one b -> 16 KB contiguous
// write per block over 4 iterations. Plain stores (fill-kernel pattern;
// NT store removed -- never A/B'd and is the prime suspect for the
// 3 TB/s write rate). Source rows i0/i1 change at most once per block
// and stay L2-hot.
// ---------------------------------------------------------------------------
__global__ __launch_bounds__(256) void k_interp(const float* __restrict__ feat2,
                                                float* __restrict__ out) {
    const int tid  = threadIdx.x;
    const int blk  = blockIdx.x;          // 0..16383
    const int b    = blk >> 9;            // 512 blocks per batch
    const int t0   = (blk & 511) * 8;     // 8 consecutive t per block
    const int d4   = tid & 127;           // float4 index within row
    const int half = tid >> 7;            // 0 or 1

#pragma unroll
    for (int it = 0; it < 4; ++it) {
        const int t = t0 + it * 2 + half;
        float pos = ((float)t + 0.5f) * (31.0f / 4096.0f) - 0.5f;
        pos = fminf(fmaxf(pos, 0.0f), 30.0f);
        const int   i0 = (int)pos;            // pos >= 0, trunc == floor
        const int   i1 = min(i0 + 1, 30);
        const float w  = pos - (float)i0;
        const float w0 = 1.0f - w;

        const f32x4* r0 = (const f32x4*)(feat2 + ((size_t)b * NW + i0) * DD);
        const f32x4* r1 = (const f32x4*)(feat2 + ((size_t)b * NW + i1) * DD);
        f32x4* o = (f32x4*)(out + ((size_t)b * TT + t) * DD);
        o[d4] = r0[d4] * w0 + r1[d4] * w;
    }
}

// ---------------------------------------------------------------------------
extern "C" void kernel_launch(void* const* d_in, const int* in_sizes, int n_in,
                              void* d_out, int out_size, void* d_ws, size_t ws_size,
                              hipStream_t stream) {
    const float* x  = (const float*)d_in[0];
    const float* W1 = (const float*)d_in[1];
    const float* b1 = (const float*)d_in[2];
    const float* W2 = (const float*)d_in[3];
    const float* b2 = (const float*)d_in[4];
    float* out = (float*)d_out;

    float* feat  = (float*)d_ws;                 // NROWS*320 floats = 1.27 MB
    float* feat2 = feat + (size_t)NROWS * 320;   // NROWS*512 floats = 2.03 MB

    k_bandpower<<<NROWS, 512, 0, stream>>>(x, feat);
    k_mlp<<<NROWS / 8, 256, 0, stream>>>(feat, W1, b1, W2, b2, feat2);
    k_interp<<<16384, 256, 0, stream>>>(feat2, out);
}

// Round 7
// 97.816 us; speedup vs baseline: 1.2804x; 1.1575x over previous
//
#include <hip/hip_runtime.h>
#include <hip/hip_bf16.h>
#include <math.h>

// Problem constants
#define BB 32
#define TT 4096
#define CC 64
#define DD 512
#define NW 31          // number of windows
#define WIN 256
#define HOP 128
#define NROWS (BB * NW)   // 992

typedef float f32x4 __attribute__((ext_vector_type(4)));

// ---------------------------------------------------------------------------
// Kernel 1: band power via folded Goertzel. (unchanged from round 4)
// ---------------------------------------------------------------------------
__global__ __launch_bounds__(512) void k_bandpower(const float* __restrict__ x,
                                                   float* __restrict__ feat) {
    __shared__ float lds[16384];         // 64 KB
    float* u = lds;                      // [128][64]
    float* v = lds + 8192;               // [128][64]

    const int tid = threadIdx.x;
    const int c   = tid & 63;
    const int g   = tid >> 6;            // wave id 0..7
    const int blk = blockIdx.x;          // 0..991
    const int b   = blk / NW;
    const int n   = blk % NW;

    // staged fold: read both halves once, write u,v (coalesced f32x4)
    const size_t winBase = ((size_t)b * TT + (size_t)n * HOP) * CC;
    const f32x4* h0 = (const f32x4*)(x + winBase);              // t = 0..127
    const f32x4* h1 = (const f32x4*)(x + winBase + 128 * CC);   // t = 128..255
    f32x4* u4 = (f32x4*)u;
    f32x4* v4 = (f32x4*)v;
    for (int i = tid; i < 2048; i += 512) {
        const f32x4 a  = h0[i];
        const f32x4 bb = h1[i];
        u4[i] = a + bb;
        v4[i] = a - bb;
    }
    __syncthreads();

    // 7 Goertzel chains per thread, 128 steps, on u (even f) or v (odd f)
    float coef[7], s1[7], s2[7];
#pragma unroll
    for (int j = 0; j < 7; ++j) {
        const int f = 1 + g + 8 * j;
        coef[j] = 2.0f * cospif((float)f * (1.0f / 128.0f)); // 2cos(2pi f/256)
        s1[j] = 0.0f;
        s2[j] = 0.0f;
    }
    // parity(f) = parity(1+g): g odd -> f even -> u; g even -> f odd -> v
    const float* src = ((g & 1) ? u : v) + c;

#pragma unroll 4
    for (int tt = 0; tt < 128; ++tt) {
        const float xv = src[tt * 64];
#pragma unroll
        for (int j = 0; j < 7; ++j) {
            const float sn = fmaf(coef[j], s1[j], xv - s2[j]);
            s2[j] = s1[j];
            s1[j] = sn;
        }
    }
    __syncthreads();   // done reading u/v; lds is re-aliased below

    // per-thread band sums
    float pb[5] = {0.0f, 0.0f, 0.0f, 0.0f, 0.0f};
#pragma unroll
    for (int j = 0; j < 7; ++j) {
        const int f = 1 + g + 8 * j;
        if (f > 50) continue;            // wave-uniform guard
        const float p = fmaf(s1[j], s1[j],
                        fmaf(s2[j], s2[j], -coef[j] * s1[j] * s2[j]));
        if (f <= 4)             pb[0] += p;
        if (f >= 4 && f <= 8)   pb[1] += p;
        if (f >= 8 && f <= 13)  pb[2] += p;
        if (f >= 13 && f <= 30) pb[3] += p;
        if (f >= 30)            pb[4] += p;
    }

    // cross-wave reduction via re-aliased LDS (each (g,k,c) written once)
    float (*bpart)[5][64] = (float (*)[5][64])lds;
#pragma unroll
    for (int k = 0; k < 5; ++k) bpart[g][k][c] = pb[k];
    __syncthreads();

    const float wband[5] = {1.0f / 4.0f, 1.0f / 5.0f, 1.0f / 6.0f,
                            1.0f / 18.0f, 1.0f / 21.0f};
    for (int idx = tid; idx < 320; idx += 512) {
        const int k  = idx >> 6;
        const int cc = idx & 63;
        float s = 0.0f;
#pragma unroll
        for (int gg = 0; gg < 8; ++gg) s += bpart[gg][k][cc];
        feat[(size_t)blk * 320 + idx] = s * wband[k];
    }
}

// ---------------------------------------------------------------------------
// Fused MLP + interp.
// One block per (b, span i), i = i0 value in [0,31). The block:
//   1. computes the MLP for feat rows (b,i) and (b,min(i+1,30)),
//   2. holds the two 512-wide output rows as registers A, D=B-A per thread,
//   3. streams out[b, t, :] = A + w(t)*D for every t in its span --
//      a load-free, memset-shaped store loop (~132 rows = 264 KB contiguous).
// Span bounds derived from the same monotone i0(pos) predicate as the
// per-t formula (analytic guess + forward scan), so assignment is exact.
// ---------------------------------------------------------------------------
__device__ __forceinline__ int i0_of(int t) {
    float pos = ((float)t + 0.5f) * (31.0f / 4096.0f) - 0.5f;
    pos = fminf(fmaxf(pos, 0.0f), 30.0f);
    return (int)pos;
}

__device__ __forceinline__ int span_start(int i) {
    if (i <= 0) return 0;
    if (i >= 31) return TT;
    int t = (int)(((float)i + 0.5f) * (4096.0f / 31.0f) - 0.5f) - 4;
    if (t < 0) t = 0;
    // first t with i0_of(t) >= i (monotone; guess is ~4 below the crossing)
    while (t < TT && i0_of(t) < i) ++t;
    return t;
}

__global__ __launch_bounds__(256) void k_mlp_interp(const float* __restrict__ feat,
                                                    const float* __restrict__ W1,
                                                    const float* __restrict__ b1,
                                                    const float* __restrict__ W2,
                                                    const float* __restrict__ b2,
                                                    float* __restrict__ out) {
    __shared__ float fs[2][320];
    __shared__ float hs[2][256];
    __shared__ float ABs[2][512];

    const int tid = threadIdx.x;
    const int blk = blockIdx.x;          // 0..991
    const int b   = blk / NW;
    const int i   = blk % NW;            // this block's i0 span
    const int r1  = min(i + 1, NW - 1);

    // stage the two feat rows
    const float* f0 = feat + ((size_t)b * NW + i) * 320;
    const float* f1 = feat + ((size_t)b * NW + r1) * 320;
    for (int k = tid; k < 320; k += 256) {
        fs[0][k] = f0[k];
        fs[1][k] = f1[k];
    }
    __syncthreads();

    // MLP phase 1: hidden (256), thread owns column tid, both rows
    {
        float a0 = b1[tid], a1 = a0;
        for (int k = 0; k < 320; ++k) {
            const float w = W1[(size_t)k * 256 + tid];
            a0 = fmaf(fs[0][k], w, a0);
            a1 = fmaf(fs[1][k], w, a1);
        }
        hs[0][tid] = fmaxf(a0, 0.0f);
        hs[1][tid] = fmaxf(a1, 0.0f);
    }
    __syncthreads();

    // MLP phase 2: output (512), thread owns columns tid, tid+256, both rows
    {
        float o00 = b2[tid], o01 = b2[tid + 256];
        float o10 = o00,     o11 = o01;
        for (int k = 0; k < 256; ++k) {
            const float w0 = W2[(size_t)k * 512 + tid];
            const float w1 = W2[(size_t)k * 512 + tid + 256];
            const float h0 = hs[0][k];
            const float h1 = hs[1][k];
            o00 = fmaf(h0, w0, o00);
            o01 = fmaf(h0, w1, o01);
            o10 = fmaf(h1, w0, o10);
            o11 = fmaf(h1, w1, o11);
        }
        ABs[0][tid] = o00; ABs[0][tid + 256] = o01;
        ABs[1][tid] = o10; ABs[1][tid + 256] = o11;
    }
    __syncthreads();

    // interp stream: res(t) = A + w(t) * (B - A), pure stores
    const int d4   = tid & 127;          // f32x4 slot within the 512-row
    const int half = tid >> 7;           // 0/1: even/odd t of each pair
    const f32x4 va = ((const f32x4*)ABs[0])[d4];
    const f32x4 vd = ((const f32x4*)ABs[1])[d4] - va;

    const int tS = span_start(i);
    const int tE = span_start(i + 1);

    for (int t = tS + half; t < tE; t += 2) {
        float pos = ((float)t + 0.5f) * (31.0f / 4096.0f) - 0.5f;
        pos = fminf(fmaxf(pos, 0.0f), 30.0f);
        const float w = pos - (float)i;
        const f32x4 res = va + w * vd;
        f32x4* o = (f32x4*)(out + ((size_t)b * TT + t) * DD);
        o[d4] = res;
    }
}

// ---------------------------------------------------------------------------
extern "C" void kernel_launch(void* const* d_in, const int* in_sizes, int n_in,
                              void* d_out, int out_size, void* d_ws, size_t ws_size,
                              hipStream_t stream) {
    const float* x  = (const float*)d_in[0];
    const float* W1 = (const float*)d_in[1];
    const float* b1 = (const float*)d_in[2];
    const float* W2 = (const float*)d_in[3];
    const float* b2 = (const float*)d_in[4];
    float* out = (float*)d_out;

    float* feat = (float*)d_ws;                  // NROWS*320 floats = 1.27 MB

    k_bandpower<<<NROWS, 512, 0, stream>>>(x, feat);
    k_mlp_interp<<<NROWS, 256, 0, stream>>>(feat, W1, b1, W2, b2, out);
}